// Round 1
// 422.723 us; speedup vs baseline: 1.1317x; 1.1317x over previous
//
#include <hip/hip_runtime.h>
#include <stdint.h>

#define S_LEN 2048
#define BATCH 8
#define EMB   1024
#define GAMMA 0.5f

typedef unsigned short ushort_t;
typedef __attribute__((ext_vector_type(8))) short  short8;
typedef __attribute__((ext_vector_type(8))) unsigned short ushort8;
typedef __attribute__((ext_vector_type(4))) float  floatx4;

__device__ __forceinline__ ushort_t f2bf(float f) {
  uint32_t x = __float_as_uint(f);
  x += 0x7fffu + ((x >> 16) & 1u);   // round-to-nearest-even
  return (ushort_t)(x >> 16);
}

__device__ __forceinline__ void gl_lds16(const ushort_t* g, ushort_t* l) {
  __builtin_amdgcn_global_load_lds(
      (const __attribute__((address_space(1))) unsigned int*)g,
      (__attribute__((address_space(3))) unsigned int*)l, 16, 0, 0);
}

// ---------------------------------------------------------------------------
// 256x256-tile 8-wave 8-phase NT bf16 GEMM core (C = A * B^T, both K-contig).
// BK=64 split into two 32-wide kslices; LDS per buffer:
//   A_s0 [0,8192) | A_s1 [8192,16384) | B_s0 [16384,24576) | B_s1 [24576,32768)
// each region 256 rows x 32 bf16 (64 B rows). Double buffered = 128 KiB.
//
// Swizzle (T2, both-sides involution since global_load_lds dest is linear):
// 16-B slot within a row is XORed with (row & 3) on BOTH the pre-swizzled
// global source and the ds_read address -> 2-way (free) bank pattern.
// ---------------------------------------------------------------------------

// Stage one 256x32 half-tile: 2 x global_load_lds(16B) per wave.
__device__ __forceinline__ void stage_half(const ushort_t* __restrict__ G,
                                           int ld, int kcol,
                                           ushort_t* lregion, int wave, int lane) {
  const int r4 = lane >> 2;
  const int slot = (lane & 3) ^ (r4 & 3);           // source pre-swizzle
  const ushort_t* g = G + (size_t)(wave * 32 + r4) * ld + kcol + slot * 8;
  gl_lds16(g, lregion + wave * 1024);
  gl_lds16(g + (size_t)16 * ld, lregion + wave * 1024 + 512);
}

__device__ __forceinline__ short8 lds_frag(const ushort_t* region, int row, int q) {
  return *(const short8*)(region + row * 32 + ((q ^ (row & 3)) << 3));
}

// barrier -> lgkmcnt(0) (+sched fence, rule #18) -> setprio(1) + 16 MFMA + setprio(0)
#define MFMA_PH(J0, J1)                                                        \
  __builtin_amdgcn_s_barrier();                                                \
  asm volatile("s_waitcnt lgkmcnt(0)" ::: "memory");                           \
  __builtin_amdgcn_sched_barrier(0);                                           \
  __builtin_amdgcn_s_setprio(1);                                               \
  _Pragma("unroll")                                                            \
  for (int i = 0; i < 8; ++i) {                                                \
    acc[i][J0] = __builtin_amdgcn_mfma_f32_16x16x32_bf16(ar[i], b0, acc[i][J0], 0, 0, 0); \
    acc[i][J1] = __builtin_amdgcn_mfma_f32_16x16x32_bf16(ar[i], b1, acc[i][J1], 0, 0, 0); \
  }                                                                            \
  __builtin_amdgcn_s_setprio(0);

__device__ __forceinline__ void gemm8_core(
    const ushort_t* __restrict__ A, const ushort_t* __restrict__ B,
    int lda, int ldb, int K, ushort_t* smem, floatx4 (&acc)[8][4])
{
  const int tid = threadIdx.x;
  const int wave = tid >> 6, lane = tid & 63;
  const int wm = wave >> 2, wn = wave & 3;      // 2 (M) x 4 (N) wave grid
  const int lr = lane & 15, q = lane >> 4;
  const int NT = K >> 6;

  // Prologue: kt0 complete (4 halves), kt1 first 3 halves. FIFO order matters.
  stage_half(A, lda, 0,  smem +     0, wave, lane);   // As0(0)
  stage_half(B, ldb, 0,  smem + 16384, wave, lane);   // Bs0(0)
  stage_half(A, lda, 32, smem +  8192, wave, lane);   // As1(0)
  stage_half(B, ldb, 32, smem + 24576, wave, lane);   // Bs1(0)
  stage_half(A, lda, 64, smem + 32768, wave, lane);   // As0(1)
  stage_half(B, ldb, 64, smem + 49152, wave, lane);   // Bs0(1)
  stage_half(A, lda, 96, smem + 40960, wave, lane);   // As1(1)
  asm volatile("s_waitcnt vmcnt(6)" ::: "memory");    // drain kt0's 8 loads
  __builtin_amdgcn_s_barrier();
  __builtin_amdgcn_sched_barrier(0);                  // no LDS-read hoist above

  const int ra = wm * 128 + lr;   // wave's A-row base
  const int rb = wn * 64 + lr;    // wave's B-row base
  short8 ar[8], b0, b1;

  for (int kt = 0; kt < NT; ++kt) {
    ushort_t* const cur = smem + (kt & 1) * 32768;
    ushort_t* const nxt = smem + ((kt & 1) ^ 1) * 32768;
    const bool st2 = (kt + 2) < NT;

    // ---- phase 0: s0 x nf{0,1}; stage Bs1(kt+1) (region dead since kt-1.p3)
#pragma unroll
    for (int i = 0; i < 8; ++i) ar[i] = lds_frag(cur, ra + i * 16, q);
    b0 = lds_frag(cur + 16384, rb,      q);
    b1 = lds_frag(cur + 16384, rb + 16, q);
    if (kt + 1 < NT) stage_half(B, ldb, (kt + 1) * 64 + 32, nxt + 24576, wave, lane);
    MFMA_PH(0, 1)
    __builtin_amdgcn_s_barrier();

    // ---- phase 1: s0 x nf{2,3}; stage As0(kt+2) (A_s0 dead after p0)
    b0 = lds_frag(cur + 16384, rb + 32, q);
    b1 = lds_frag(cur + 16384, rb + 48, q);
    if (st2) stage_half(A, lda, (kt + 2) * 64, cur, wave, lane);
    MFMA_PH(2, 3)
    __builtin_amdgcn_s_barrier();

    // ---- phase 2: s1 x nf{0,1}; stage Bs0(kt+2) (B_s0 dead after p1)
#pragma unroll
    for (int i = 0; i < 8; ++i) ar[i] = lds_frag(cur + 8192, ra + i * 16, q);
    b0 = lds_frag(cur + 24576, rb,      q);
    b1 = lds_frag(cur + 24576, rb + 16, q);
    if (st2) stage_half(B, ldb, (kt + 2) * 64, cur + 16384, wave, lane);
    MFMA_PH(0, 1)
    __builtin_amdgcn_s_barrier();

    // ---- phase 3: s1 x nf{2,3}; stage As1(kt+2) (A_s1 dead after p2);
    //              boundary vmcnt: drain through Bs1(kt+1), keep kt+2's 6.
    b0 = lds_frag(cur + 24576, rb + 32, q);
    b1 = lds_frag(cur + 24576, rb + 48, q);
    if (st2) stage_half(A, lda, (kt + 2) * 64 + 32, cur + 8192, wave, lane);
    MFMA_PH(2, 3)
    if (st2)              { asm volatile("s_waitcnt vmcnt(6)" ::: "memory"); }
    else if (kt + 1 < NT) { asm volatile("s_waitcnt vmcnt(0)" ::: "memory"); }
    __builtin_amdgcn_s_barrier();
  }
}

// ---------- quantize / pack ----------
__global__ __launch_bounds__(256) void k_quant_x(const float* __restrict__ X,
                                                 ushort_t* __restrict__ Xb) {
  size_t i = ((size_t)blockIdx.x * 256 + threadIdx.x) * 4;
  float4 v = *(const float4*)(X + i);
  *(ushort4*)(Xb + i) = make_ushort4(f2bf(v.x), f2bf(v.y), f2bf(v.z), f2bf(v.w));
}

__global__ __launch_bounds__(256) void k_quant_w(
    const float* __restrict__ Wq, const float* __restrict__ Wk,
    const float* __restrict__ Wv, ushort_t* __restrict__ W) {
  size_t i = ((size_t)blockIdx.x * 256 + threadIdx.x) * 4;
  int row = (int)(i >> 10), col = (int)(i & 1023);
  int sel = row >> 10, sr = row & 1023;
  const float* src = sel == 0 ? Wq : (sel == 1 ? Wk : Wv);
  float4 v = *(const float4*)(src + (size_t)sr * 1024 + col);
  *(ushort4*)(W + i) = make_ushort4(f2bf(v.x), f2bf(v.y), f2bf(v.z), f2bf(v.w));
}

__global__ __launch_bounds__(256) void k_bias_zero(
    const float* __restrict__ bq, const float* __restrict__ bk,
    const float* __restrict__ bv, float* __restrict__ bias,
    float* __restrict__ q2, float* __restrict__ k2, float* __restrict__ rsum) {
  int i = blockIdx.x * 256 + threadIdx.x;
  if (i < 1024)       bias[i] = bq[i];
  else if (i < 2048)  bias[i] = bk[i - 1024];
  else if (i < 3072)  bias[i] = bv[i - 2048];
  if (i < BATCH * S_LEN) { q2[i] = 0.f; k2[i] = 0.f; rsum[i] = 0.f; }
}

// ---------- GEMM 1: QKV projection (M=16384, N=3072, K=1024) ----------
__global__ __launch_bounds__(512, 2) void k_gemm_qkv(
    const ushort_t* __restrict__ Xb, const ushort_t* __restrict__ W,
    const float* __restrict__ bias,
    ushort_t* __restrict__ Q, ushort_t* __restrict__ Kp, ushort_t* __restrict__ V,
    float* __restrict__ q2, float* __restrict__ k2) {
  __shared__ __attribute__((aligned(16))) ushort_t smem[65536];
  const int mt = blockIdx.x * 256, nt = blockIdx.y * 256;
  floatx4 acc[8][4];
  const floatx4 z = {0.f, 0.f, 0.f, 0.f};
#pragma unroll
  for (int i = 0; i < 8; ++i)
#pragma unroll
    for (int j = 0; j < 4; ++j) acc[i][j] = z;

  gemm8_core(Xb + (size_t)mt * EMB, W + (size_t)nt * EMB, EMB, EMB, EMB, smem, acc);

  const int lane = threadIdx.x & 63, wave = threadIdx.x >> 6;
  const int wm = wave >> 2, wn = wave & 3;
  const int lr = lane & 15, q = lane >> 4;
  const int which = nt >> 10;        // 0=q 1=k 2=v  (256 | 1024 so no straddle)
  const int nc0 = nt & 1023;
  ushort_t* dst = which == 0 ? Q : (which == 1 ? Kp : V);
  float* sq = which == 0 ? q2 : k2;
  float bv4[4];
#pragma unroll
  for (int j = 0; j < 4; ++j) bv4[j] = bias[nt + wn * 64 + j * 16 + lr];

#pragma unroll
  for (int i = 0; i < 8; ++i) {
#pragma unroll
    for (int r = 0; r < 4; ++r) {
      const int g = mt + wm * 128 + i * 16 + q * 4 + r;
      const int t = g >> 3, b = g & 7;
      float ss = 0.f;
#pragma unroll
      for (int j = 0; j < 4; ++j) {
        const float val = acc[i][j][r] + bv4[j];
        dst[(size_t)(b * S_LEN + t) * EMB + nc0 + wn * 64 + j * 16 + lr] = f2bf(val);
        ss += val * val;
      }
      if (which < 2) {
        ss += __shfl_xor(ss, 1);
        ss += __shfl_xor(ss, 2);
        ss += __shfl_xor(ss, 4);
        ss += __shfl_xor(ss, 8);
        if (lr == 0) atomicAdd(&sq[b * S_LEN + t], ss);
      }
    }
  }
}

// ---------- transpose V[b][j][e] -> Vt[b][e][j] ----------
__global__ __launch_bounds__(256) void k_transpose(const ushort_t* __restrict__ V,
                                                   ushort_t* __restrict__ Vt) {
  __shared__ ushort_t tile[64][72];
  const int b = blockIdx.z, j0 = blockIdx.x * 64, e0 = blockIdx.y * 64;
  const ushort_t* src = V + ((size_t)b * S_LEN + j0) * EMB + e0;
  const int tid = threadIdx.x;
#pragma unroll
  for (int rep = 0; rep < 2; ++rep) {
    const int lin = rep * 256 + tid;
    const int j = lin >> 3, e8 = (lin & 7) * 8;
    *(uint4*)&tile[j][e8] = *(const uint4*)(src + (size_t)j * EMB + e8);
  }
  __syncthreads();
  ushort_t* dst = Vt + ((size_t)b * EMB + e0) * S_LEN + j0;
#pragma unroll
  for (int rep = 0; rep < 2; ++rep) {
    const int lin = rep * 256 + tid;
    const int e = lin >> 3, j8 = (lin & 7) * 8;
    ushort8 o;
#pragma unroll
    for (int m = 0; m < 8; ++m) o[m] = tile[j8 + m][e];
    *(ushort8*)(dst + (size_t)e * S_LEN + j8) = o;
  }
}

// ---------- GEMM 2: logits + exp (per batch: 2048 x 2048 x 1024) ----------
__global__ __launch_bounds__(512, 2) void k_logits(
    const ushort_t* __restrict__ Q, const ushort_t* __restrict__ Kp,
    const float* __restrict__ q2, const float* __restrict__ k2,
    ushort_t* __restrict__ P, float* __restrict__ rsum) {
  __shared__ __attribute__((aligned(16))) ushort_t smem[65536];
  const int b = blockIdx.z;
  const int mt = blockIdx.x * 256, nt = blockIdx.y * 256;
  floatx4 acc[8][4];
  const floatx4 z = {0.f, 0.f, 0.f, 0.f};
#pragma unroll
  for (int i = 0; i < 8; ++i)
#pragma unroll
    for (int j = 0; j < 4; ++j) acc[i][j] = z;

  gemm8_core(Q + ((size_t)b * S_LEN + mt) * EMB,
             Kp + ((size_t)b * S_LEN + nt) * EMB, EMB, EMB, EMB, smem, acc);

  const int lane = threadIdx.x & 63, wave = threadIdx.x >> 6;
  const int wm = wave >> 2, wn = wave & 3;
  const int lr = lane & 15, q = lane >> 4;
  float k2v[4];
#pragma unroll
  for (int j = 0; j < 4; ++j) k2v[j] = k2[b * S_LEN + nt + wn * 64 + j * 16 + lr];

#pragma unroll
  for (int i = 0; i < 8; ++i) {
#pragma unroll
    for (int r = 0; r < 4; ++r) {
      const int t = mt + wm * 128 + i * 16 + q * 4 + r;
      const float q2v = q2[b * S_LEN + t];
      float ss = 0.f;
#pragma unroll
      for (int j = 0; j < 4; ++j) {
        float d2 = q2v + k2v[j] - 2.f * acc[i][j][r];
        d2 = fmaxf(d2, 0.f);
        const float p = __expf(-GAMMA * d2);
        P[((size_t)b * S_LEN + t) * S_LEN + nt + wn * 64 + j * 16 + lr] = f2bf(p);
        ss += p;
      }
      ss += __shfl_xor(ss, 1);
      ss += __shfl_xor(ss, 2);
      ss += __shfl_xor(ss, 4);
      ss += __shfl_xor(ss, 8);
      if (lr == 0) atomicAdd(&rsum[b * S_LEN + t], ss);
    }
  }
}

// ---------- GEMM 3: O = (P @ V) / rowsum (per batch: 2048 x 1024 x 2048) ----------
__global__ __launch_bounds__(512, 2) void k_out(
    const ushort_t* __restrict__ P, const ushort_t* __restrict__ Vt,
    const float* __restrict__ rsum, float* __restrict__ out) {
  __shared__ __attribute__((aligned(16))) ushort_t smem[65536];
  const int b = blockIdx.z;
  const int mt = blockIdx.x * 256, nt = blockIdx.y * 256;
  floatx4 acc[8][4];
  const floatx4 z = {0.f, 0.f, 0.f, 0.f};
#pragma unroll
  for (int i = 0; i < 8; ++i)
#pragma unroll
    for (int j = 0; j < 4; ++j) acc[i][j] = z;

  gemm8_core(P + ((size_t)b * S_LEN + mt) * S_LEN,
             Vt + ((size_t)b * EMB + nt) * S_LEN, S_LEN, S_LEN, S_LEN, smem, acc);

  const int lane = threadIdx.x & 63, wave = threadIdx.x >> 6;
  const int wm = wave >> 2, wn = wave & 3;
  const int lr = lane & 15, q = lane >> 4;
#pragma unroll
  for (int i = 0; i < 8; ++i) {
#pragma unroll
    for (int r = 0; r < 4; ++r) {
      const int t = mt + wm * 128 + i * 16 + q * 4 + r;
      const float rinv = 1.f / rsum[b * S_LEN + t];
#pragma unroll
      for (int j = 0; j < 4; ++j) {
        const int e = nt + wn * 64 + j * 16 + lr;
        out[((size_t)t * BATCH + b) * EMB + e] = acc[i][j][r] * rinv;
      }
    }
  }
}

extern "C" void kernel_launch(void* const* d_in, const int* in_sizes, int n_in,
                              void* d_out, int out_size, void* d_ws, size_t ws_size,
                              hipStream_t stream) {
  (void)in_sizes; (void)n_in; (void)out_size; (void)ws_size;
  const float* X  = (const float*)d_in[0];
  const float* Wq = (const float*)d_in[1];
  const float* bq = (const float*)d_in[2];
  const float* Wk = (const float*)d_in[3];
  const float* bk = (const float*)d_in[4];
  const float* Wv = (const float*)d_in[5];
  const float* bv = (const float*)d_in[6];
  float* out = (float*)d_out;
  char* ws = (char*)d_ws;

  // workspace layout (bytes); Xb aliases P (Xb dead before P is written)
  ushort_t* Q    = (ushort_t*)(ws + 0);           //  33,554,432
  ushort_t* Kp   = (ushort_t*)(ws + 33554432);    //  33,554,432
  ushort_t* V    = (ushort_t*)(ws + 67108864);    //  33,554,432
  ushort_t* Vt   = (ushort_t*)(ws + 100663296);   //  33,554,432
  ushort_t* P    = (ushort_t*)(ws + 134217728);   //  67,108,864
  ushort_t* Xb   = (ushort_t*)(ws + 134217728);   //  alias of P[0:33.5M]
  ushort_t* Wqkv = (ushort_t*)(ws + 201326592);   //   6,291,456
  float*    bias = (float*)(ws + 207618048);      //      12,288
  float*    q2   = (float*)(ws + 207630336);      //      65,536
  float*    k2   = (float*)(ws + 207695872);      //      65,536
  float*    rsum = (float*)(ws + 207761408);      //      65,536  -> total ~198 MiB

  k_quant_x <<<16384, 256, 0, stream>>>(X, Xb);
  k_quant_w <<<3072, 256, 0, stream>>>(Wq, Wk, Wv, Wqkv);
  k_bias_zero<<<64, 256, 0, stream>>>(bq, bk, bv, bias, q2, k2, rsum);
  k_gemm_qkv<<<dim3(64, 12), 512, 0, stream>>>(Xb, Wqkv, bias, Q, Kp, V, q2, k2);
  k_transpose<<<dim3(32, 16, 8), 256, 0, stream>>>(V, Vt);
  k_logits  <<<dim3(8, 8, 8), 512, 0, stream>>>(Q, Kp, q2, k2, P, rsum);
  k_out     <<<dim3(8, 4, 8), 512, 0, stream>>>(P, Vt, rsum, out);
}

// Round 3
// 407.919 us; speedup vs baseline: 1.1728x; 1.0363x over previous
//
#include <hip/hip_runtime.h>
#include <stdint.h>

#define S_LEN 2048
#define BATCH 8
#define EMB   1024
#define GAMMA 0.5f

typedef unsigned short ushort_t;
typedef __attribute__((ext_vector_type(8))) short  short8;
typedef __attribute__((ext_vector_type(8))) unsigned short ushort8;
typedef __attribute__((ext_vector_type(4))) float  floatx4;

__device__ __forceinline__ ushort_t f2bf(float f) {
  uint32_t x = __float_as_uint(f);
  x += 0x7fffu + ((x >> 16) & 1u);   // round-to-nearest-even
  return (ushort_t)(x >> 16);
}

__device__ __forceinline__ void gl_lds16(const ushort_t* g, ushort_t* l) {
  __builtin_amdgcn_global_load_lds(
      (const __attribute__((address_space(1))) unsigned int*)g,
      (__attribute__((address_space(3))) unsigned int*)l, 16, 0, 0);
}

// ---------------------------------------------------------------------------
// 256x256-tile 8-wave 8-phase NT bf16 GEMM core (C = A * B^T, both K-contig).
// BK=64 split into two 32-wide kslices; LDS per buffer:
//   A_s0 [0,8192) | A_s1 [8192,16384) | B_s0 [16384,24576) | B_s1 [24576,32768)
// each region 256 rows x 32 bf16 (64 B rows). Double buffered = 128 KiB.
//
// Swizzle (corrected R3): rows are 64 B -> a row's bank-group repeats every
// TWO rows (64 B = 16 banks). Involution must therefore be
//   slot ^= (row >> 1) & 3
// so rows 0..7 of an 8-lane read group cover all 32 banks disjointly
// (the old  slot ^= row&3  left rows r, r+4 on identical banks -> 4-way).
// Applied on the pre-swizzled GLOBAL source (global_load_lds dest stays
// linear) and identically on the ds_read address.
//
// Sync structure (proven correct in R1): reads at phase start are covered by
// a vmcnt executed BEFORE the previous phase's barrier (vmcnt -> s_barrier ->
// ds_read gives cross-wave visibility of all waves' global_load_lds writes).
// ---------------------------------------------------------------------------

// Stage one 256x32 half-tile: 2 x global_load_lds(16B) per wave.
__device__ __forceinline__ void stage_half(const ushort_t* __restrict__ G,
                                           int ld, int kcol,
                                           ushort_t* lregion, int wave, int lane) {
  const int r4 = lane >> 2;
  const int slot = (lane & 3) ^ ((r4 >> 1) & 3);    // source pre-swizzle
  const ushort_t* g = G + (size_t)(wave * 32 + r4) * ld + kcol + slot * 8;
  gl_lds16(g, lregion + wave * 1024);
  gl_lds16(g + (size_t)16 * ld, lregion + wave * 1024 + 512);
}

__device__ __forceinline__ short8 lds_frag(const ushort_t* region, int row, int q) {
  return *(const short8*)(region + row * 32 + (((q ^ (row >> 1)) & 3) << 3));
}

// barrier -> lgkmcnt(0) (+sched fence, rule #18) -> setprio(1) + 16 MFMA + setprio(0)
#define MFMA_PH(J0, J1)                                                        \
  __builtin_amdgcn_s_barrier();                                                \
  asm volatile("s_waitcnt lgkmcnt(0)" ::: "memory");                           \
  __builtin_amdgcn_sched_barrier(0);                                           \
  __builtin_amdgcn_s_setprio(1);                                               \
  _Pragma("unroll")                                                            \
  for (int i = 0; i < 8; ++i) {                                                \
    acc[i][J0] = __builtin_amdgcn_mfma_f32_16x16x32_bf16(ar[i], b0, acc[i][J0], 0, 0, 0); \
    acc[i][J1] = __builtin_amdgcn_mfma_f32_16x16x32_bf16(ar[i], b1, acc[i][J1], 0, 0, 0); \
  }                                                                            \
  __builtin_amdgcn_s_setprio(0);

__device__ __forceinline__ void gemm8_core(
    const ushort_t* __restrict__ A, const ushort_t* __restrict__ B,
    int lda, int ldb, int K, ushort_t* smem, floatx4 (&acc)[8][4])
{
  const int tid = threadIdx.x;
  const int wave = tid >> 6, lane = tid & 63;
  const int wm = wave >> 2, wn = wave & 3;      // 2 (M) x 4 (N) wave grid
  const int lr = lane & 15, q = lane >> 4;
  const int NT = K >> 6;

  // Prologue: kt0 complete (4 halves), kt1 first 3 halves. FIFO order matters.
  stage_half(A, lda, 0,  smem +     0, wave, lane);   // As0(0)
  stage_half(B, ldb, 0,  smem + 16384, wave, lane);   // Bs0(0)
  stage_half(A, lda, 32, smem +  8192, wave, lane);   // As1(0)
  stage_half(B, ldb, 32, smem + 24576, wave, lane);   // Bs1(0)
  stage_half(A, lda, 64, smem + 32768, wave, lane);   // As0(1)
  stage_half(B, ldb, 64, smem + 49152, wave, lane);   // Bs0(1)
  stage_half(A, lda, 96, smem + 40960, wave, lane);   // As1(1)
  asm volatile("s_waitcnt vmcnt(6)" ::: "memory");    // drain kt0's 8 loads
  __builtin_amdgcn_s_barrier();
  __builtin_amdgcn_sched_barrier(0);                  // no LDS-read hoist above

  const int ra = wm * 128 + lr;   // wave's A-row base
  const int rb = wn * 64 + lr;    // wave's B-row base
  short8 ar[8], b0, b1;

  for (int kt = 0; kt < NT; ++kt) {
    ushort_t* const cur = smem + (kt & 1) * 32768;
    ushort_t* const nxt = smem + ((kt & 1) ^ 1) * 32768;
    const bool st2 = (kt + 2) < NT;

    // ---- phase 0: s0 x nf{0,1}; stage Bs1(kt+1) (region dead since kt-1.p3)
#pragma unroll
    for (int i = 0; i < 8; ++i) ar[i] = lds_frag(cur, ra + i * 16, q);
    b0 = lds_frag(cur + 16384, rb,      q);
    b1 = lds_frag(cur + 16384, rb + 16, q);
    if (kt + 1 < NT) stage_half(B, ldb, (kt + 1) * 64 + 32, nxt + 24576, wave, lane);
    MFMA_PH(0, 1)
    __builtin_amdgcn_s_barrier();

    // ---- phase 1: s0 x nf{2,3}; stage As0(kt+2) (A_s0 dead after p0)
    b0 = lds_frag(cur + 16384, rb + 32, q);
    b1 = lds_frag(cur + 16384, rb + 48, q);
    if (st2) stage_half(A, lda, (kt + 2) * 64, cur, wave, lane);
    MFMA_PH(2, 3)
    __builtin_amdgcn_s_barrier();

    // ---- phase 2: s1 x nf{0,1}; stage Bs0(kt+2) (B_s0 dead after p1)
#pragma unroll
    for (int i = 0; i < 8; ++i) ar[i] = lds_frag(cur + 8192, ra + i * 16, q);
    b0 = lds_frag(cur + 24576, rb,      q);
    b1 = lds_frag(cur + 24576, rb + 16, q);
    if (st2) stage_half(B, ldb, (kt + 2) * 64, cur + 16384, wave, lane);
    MFMA_PH(0, 1)
    __builtin_amdgcn_s_barrier();

    // ---- phase 3: s1 x nf{2,3}; stage As1(kt+2) (A_s1 dead after p2);
    //              boundary vmcnt: drain through Bs1(kt+1), keep kt+2's 6.
    b0 = lds_frag(cur + 24576, rb + 32, q);
    b1 = lds_frag(cur + 24576, rb + 48, q);
    if (st2) stage_half(A, lda, (kt + 2) * 64 + 32, cur + 8192, wave, lane);
    MFMA_PH(2, 3)
    if (st2)              { asm volatile("s_waitcnt vmcnt(6)" ::: "memory"); }
    else if (kt + 1 < NT) { asm volatile("s_waitcnt vmcnt(0)" ::: "memory"); }
    __builtin_amdgcn_s_barrier();
  }
}

// ---------- quantize / pack ----------
__global__ __launch_bounds__(256) void k_quant_x(const float* __restrict__ X,
                                                 ushort_t* __restrict__ Xb) {
  size_t i = ((size_t)blockIdx.x * 256 + threadIdx.x) * 4;
  float4 v = *(const float4*)(X + i);
  *(ushort4*)(Xb + i) = make_ushort4(f2bf(v.x), f2bf(v.y), f2bf(v.z), f2bf(v.w));
}

__global__ __launch_bounds__(256) void k_quant_w(
    const float* __restrict__ Wq, const float* __restrict__ Wk,
    const float* __restrict__ Wv, ushort_t* __restrict__ W) {
  size_t i = ((size_t)blockIdx.x * 256 + threadIdx.x) * 4;
  int row = (int)(i >> 10), col = (int)(i & 1023);
  int sel = row >> 10, sr = row & 1023;
  const float* src = sel == 0 ? Wq : (sel == 1 ? Wk : Wv);
  float4 v = *(const float4*)(src + (size_t)sr * 1024 + col);
  *(ushort4*)(W + i) = make_ushort4(f2bf(v.x), f2bf(v.y), f2bf(v.z), f2bf(v.w));
}

__global__ __launch_bounds__(256) void k_bias_zero(
    const float* __restrict__ bq, const float* __restrict__ bk,
    const float* __restrict__ bv, float* __restrict__ bias,
    float* __restrict__ q2, float* __restrict__ k2, float* __restrict__ rsum) {
  int i = blockIdx.x * 256 + threadIdx.x;
  if (i < 1024)       bias[i] = bq[i];
  else if (i < 2048)  bias[i] = bk[i - 1024];
  else if (i < 3072)  bias[i] = bv[i - 2048];
  if (i < BATCH * S_LEN) { q2[i] = 0.f; k2[i] = 0.f; rsum[i] = 0.f; }
}

// ---------- GEMM 1: QKV projection (M=16384, N=3072, K=1024) ----------
__global__ __launch_bounds__(512, 2) void k_gemm_qkv(
    const ushort_t* __restrict__ Xb, const ushort_t* __restrict__ W,
    const float* __restrict__ bias,
    ushort_t* __restrict__ Q, ushort_t* __restrict__ Kp, ushort_t* __restrict__ V,
    float* __restrict__ q2, float* __restrict__ k2) {
  __shared__ __attribute__((aligned(16))) ushort_t smem[65536];
  const int mt = blockIdx.x * 256, nt = blockIdx.y * 256;
  floatx4 acc[8][4];
  const floatx4 z = {0.f, 0.f, 0.f, 0.f};
#pragma unroll
  for (int i = 0; i < 8; ++i)
#pragma unroll
    for (int j = 0; j < 4; ++j) acc[i][j] = z;

  gemm8_core(Xb + (size_t)mt * EMB, W + (size_t)nt * EMB, EMB, EMB, EMB, smem, acc);

  const int lane = threadIdx.x & 63, wave = threadIdx.x >> 6;
  const int wm = wave >> 2, wn = wave & 3;
  const int lr = lane & 15, q = lane >> 4;
  const int which = nt >> 10;        // 0=q 1=k 2=v  (256 | 1024 so no straddle)
  const int nc0 = nt & 1023;
  ushort_t* dst = which == 0 ? Q : (which == 1 ? Kp : V);
  float* sq = which == 0 ? q2 : k2;
  float bv4[4];
#pragma unroll
  for (int j = 0; j < 4; ++j) bv4[j] = bias[nt + wn * 64 + j * 16 + lr];

#pragma unroll
  for (int i = 0; i < 8; ++i) {
#pragma unroll
    for (int r = 0; r < 4; ++r) {
      const int g = mt + wm * 128 + i * 16 + q * 4 + r;
      const int t = g >> 3, b = g & 7;
      float ss = 0.f;
#pragma unroll
      for (int j = 0; j < 4; ++j) {
        const float val = acc[i][j][r] + bv4[j];
        dst[(size_t)(b * S_LEN + t) * EMB + nc0 + wn * 64 + j * 16 + lr] = f2bf(val);
        ss += val * val;
      }
      if (which < 2) {
        ss += __shfl_xor(ss, 1);
        ss += __shfl_xor(ss, 2);
        ss += __shfl_xor(ss, 4);
        ss += __shfl_xor(ss, 8);
        if (lr == 0) atomicAdd(&sq[b * S_LEN + t], ss);
      }
    }
  }
}

// ---------- transpose V[b][j][e] -> Vt[b][e][j] ----------
__global__ __launch_bounds__(256) void k_transpose(const ushort_t* __restrict__ V,
                                                   ushort_t* __restrict__ Vt) {
  __shared__ ushort_t tile[64][72];
  const int b = blockIdx.z, j0 = blockIdx.x * 64, e0 = blockIdx.y * 64;
  const ushort_t* src = V + ((size_t)b * S_LEN + j0) * EMB + e0;
  const int tid = threadIdx.x;
#pragma unroll
  for (int rep = 0; rep < 2; ++rep) {
    const int lin = rep * 256 + tid;
    const int j = lin >> 3, e8 = (lin & 7) * 8;
    *(uint4*)&tile[j][e8] = *(const uint4*)(src + (size_t)j * EMB + e8);
  }
  __syncthreads();
  ushort_t* dst = Vt + ((size_t)b * EMB + e0) * S_LEN + j0;
#pragma unroll
  for (int rep = 0; rep < 2; ++rep) {
    const int lin = rep * 256 + tid;
    const int e = lin >> 3, j8 = (lin & 7) * 8;
    ushort8 o;
#pragma unroll
    for (int m = 0; m < 8; ++m) o[m] = tile[j8 + m][e];
    *(ushort8*)(dst + (size_t)e * S_LEN + j8) = o;
  }
}

// ---------- GEMM 2: logits + exp (per batch: 2048 x 2048 x 1024) ----------
__global__ __launch_bounds__(512, 2) void k_logits(
    const ushort_t* __restrict__ Q, const ushort_t* __restrict__ Kp,
    const float* __restrict__ q2, const float* __restrict__ k2,
    ushort_t* __restrict__ P, float* __restrict__ rsum) {
  __shared__ __attribute__((aligned(16))) ushort_t smem[65536];
  const int b = blockIdx.z;
  const int mt = blockIdx.x * 256, nt = blockIdx.y * 256;
  floatx4 acc[8][4];
  const floatx4 z = {0.f, 0.f, 0.f, 0.f};
#pragma unroll
  for (int i = 0; i < 8; ++i)
#pragma unroll
    for (int j = 0; j < 4; ++j) acc[i][j] = z;

  gemm8_core(Q + ((size_t)b * S_LEN + mt) * EMB,
             Kp + ((size_t)b * S_LEN + nt) * EMB, EMB, EMB, EMB, smem, acc);

  const int lane = threadIdx.x & 63, wave = threadIdx.x >> 6;
  const int wm = wave >> 2, wn = wave & 3;
  const int lr = lane & 15, q = lane >> 4;
  float k2v[4];
#pragma unroll
  for (int j = 0; j < 4; ++j) k2v[j] = k2[b * S_LEN + nt + wn * 64 + j * 16 + lr];

#pragma unroll
  for (int i = 0; i < 8; ++i) {
#pragma unroll
    for (int r = 0; r < 4; ++r) {
      const int t = mt + wm * 128 + i * 16 + q * 4 + r;
      const float q2v = q2[b * S_LEN + t];
      float ss = 0.f;
#pragma unroll
      for (int j = 0; j < 4; ++j) {
        float d2 = q2v + k2v[j] - 2.f * acc[i][j][r];
        d2 = fmaxf(d2, 0.f);
        const float p = __expf(-GAMMA * d2);
        P[((size_t)b * S_LEN + t) * S_LEN + nt + wn * 64 + j * 16 + lr] = f2bf(p);
        ss += p;
      }
      ss += __shfl_xor(ss, 1);
      ss += __shfl_xor(ss, 2);
      ss += __shfl_xor(ss, 4);
      ss += __shfl_xor(ss, 8);
      if (lr == 0) atomicAdd(&rsum[b * S_LEN + t], ss);
    }
  }
}

// ---------- GEMM 3: O = (P @ V) / rowsum (per batch: 2048 x 1024 x 2048) ----------
__global__ __launch_bounds__(512, 2) void k_out(
    const ushort_t* __restrict__ P, const ushort_t* __restrict__ Vt,
    const float* __restrict__ rsum, float* __restrict__ out) {
  __shared__ __attribute__((aligned(16))) ushort_t smem[65536];
  const int b = blockIdx.z;
  const int mt = blockIdx.x * 256, nt = blockIdx.y * 256;
  floatx4 acc[8][4];
  const floatx4 z = {0.f, 0.f, 0.f, 0.f};
#pragma unroll
  for (int i = 0; i < 8; ++i)
#pragma unroll
    for (int j = 0; j < 4; ++j) acc[i][j] = z;

  gemm8_core(P + ((size_t)b * S_LEN + mt) * S_LEN,
             Vt + ((size_t)b * EMB + nt) * S_LEN, S_LEN, S_LEN, S_LEN, smem, acc);

  const int lane = threadIdx.x & 63, wave = threadIdx.x >> 6;
  const int wm = wave >> 2, wn = wave & 3;
  const int lr = lane & 15, q = lane >> 4;
#pragma unroll
  for (int i = 0; i < 8; ++i) {
#pragma unroll
    for (int r = 0; r < 4; ++r) {
      const int t = mt + wm * 128 + i * 16 + q * 4 + r;
      const float rinv = 1.f / rsum[b * S_LEN + t];
#pragma unroll
      for (int j = 0; j < 4; ++j) {
        const int e = nt + wn * 64 + j * 16 + lr;
        out[((size_t)t * BATCH + b) * EMB + e] = acc[i][j][r] * rinv;
      }
    }
  }
}

extern "C" void kernel_launch(void* const* d_in, const int* in_sizes, int n_in,
                              void* d_out, int out_size, void* d_ws, size_t ws_size,
                              hipStream_t stream) {
  (void)in_sizes; (void)n_in; (void)out_size; (void)ws_size;
  const float* X  = (const float*)d_in[0];
  const float* Wq = (const float*)d_in[1];
  const float* bq = (const float*)d_in[2];
  const float* Wk = (const float*)d_in[3];
  const float* bk = (const float*)d_in[4];
  const float* Wv = (const float*)d_in[5];
  const float* bv = (const float*)d_in[6];
  float* out = (float*)d_out;
  char* ws = (char*)d_ws;

  // workspace layout (bytes); Xb aliases P (Xb dead before P is written)
  ushort_t* Q    = (ushort_t*)(ws + 0);           //  33,554,432
  ushort_t* Kp   = (ushort_t*)(ws + 33554432);    //  33,554,432
  ushort_t* V    = (ushort_t*)(ws + 67108864);    //  33,554,432
  ushort_t* Vt   = (ushort_t*)(ws + 100663296);   //  33,554,432
  ushort_t* P    = (ushort_t*)(ws + 134217728);   //  67,108,864
  ushort_t* Xb   = (ushort_t*)(ws + 134217728);   //  alias of P[0:33.5M]
  ushort_t* Wqkv = (ushort_t*)(ws + 201326592);   //   6,291,456
  float*    bias = (float*)(ws + 207618048);      //      12,288
  float*    q2   = (float*)(ws + 207630336);      //      65,536
  float*    k2   = (float*)(ws + 207695872);      //      65,536
  float*    rsum = (float*)(ws + 207761408);      //      65,536  -> total ~198 MiB

  k_quant_x <<<16384, 256, 0, stream>>>(X, Xb);
  k_quant_w <<<3072, 256, 0, stream>>>(Wq, Wk, Wv, Wqkv);
  k_bias_zero<<<64, 256, 0, stream>>>(bq, bk, bv, bias, q2, k2, rsum);
  k_gemm_qkv<<<dim3(64, 12), 512, 0, stream>>>(Xb, Wqkv, bias, Q, Kp, V, q2, k2);
  k_transpose<<<dim3(32, 16, 8), 256, 0, stream>>>(V, Vt);
  k_logits  <<<dim3(8, 8, 8), 512, 0, stream>>>(Q, Kp, q2, k2, P, rsum);
  k_out     <<<dim3(8, 4, 8), 512, 0, stream>>>(P, Vt, rsum, out);
}

// Round 4
// 403.362 us; speedup vs baseline: 1.1860x; 1.0113x over previous
//
#include <hip/hip_runtime.h>
#include <stdint.h>

#define S_LEN 2048
#define BATCH 8
#define EMB   1024
#define GAMMA 0.5f

typedef unsigned short ushort_t;
typedef __attribute__((ext_vector_type(8))) short  short8;
typedef __attribute__((ext_vector_type(8))) unsigned short ushort8;
typedef __attribute__((ext_vector_type(4))) float  floatx4;

__device__ __forceinline__ ushort_t f2bf(float f) {
  uint32_t x = __float_as_uint(f);
  x += 0x7fffu + ((x >> 16) & 1u);   // round-to-nearest-even
  return (ushort_t)(x >> 16);
}

__device__ __forceinline__ void gl_lds16(const ushort_t* g, ushort_t* l) {
  __builtin_amdgcn_global_load_lds(
      (const __attribute__((address_space(1))) unsigned int*)g,
      (__attribute__((address_space(3))) unsigned int*)l, 16, 0, 0);
}

// ---------------------------------------------------------------------------
// 256x256-tile 8-wave software-pipelined NT bf16 GEMM core (C = A * B^T).
// BK=64 as two 32-wide kslices; LDS regions (ushort offsets, per buffer):
//   As0 +0 | As1 +8192 | Bs0 +16384 | Bs1 +24576 ; regions 256r x 32 bf16.
// Double buffered = 128 KiB. Swizzle: slot ^= (row>>1)&3 on both the
// pre-swizzled global source and the ds_read address (R3, conflict-free).
//
// R4 pipeline: each phase's ds_reads are issued in the PREVIOUS phase's MFMA
// interval (no reg dependency on in-flight MFMA -> reads drain under MFMA +
// barrier wait; lgkmcnt(0) at next interval start catches them). 4 barriers
// per K-tile (was 8), zero read-only intervals.
//   I_0: lgkm0; MFMA(s0,nf01); pf t0,t1=Bs0 r32/48, ar2[0..3]; stage Bs1(kt+1)->nxt
//   I_1: lgkm0; MFMA(s0,nf23); pf ar2[4..7], u0,u1=Bs1 r0/16; stage As0(kt+2)->cur
//   I_2: lgkm0; MFMA(s1,nf01); pf t0,t1=Bs1 r32/48; stage Bs0(kt+2)->cur; vmcnt(4)
//   I_3: lgkm0; MFMA(s1,nf23); pf ar,b0,b1 from NXT (kt+1 p0); stage As1(kt+2)->cur
// vmcnt(4) ledger @I_2 end: keep newest 2 stages (As0/Bs0(kt+2)); drains all
// of kt+1's regions -> the I_3 nxt-prefetch obeys vmcnt -> s_barrier -> ds_read
// (cross-wave visibility; the invariant R2 violated). Every stage is issued
// after a barrier that follows all readers' lgkm-drain (checked per region).
// ---------------------------------------------------------------------------

__device__ __forceinline__ void stage_half(const ushort_t* __restrict__ G,
                                           int ld, int kcol,
                                           ushort_t* lregion, int wave, int lane) {
  const int r4 = lane >> 2;
  const int slot = (lane & 3) ^ ((r4 >> 1) & 3);    // source pre-swizzle
  const ushort_t* g = G + (size_t)(wave * 32 + r4) * ld + kcol + slot * 8;
  gl_lds16(g, lregion + wave * 1024);
  gl_lds16(g + (size_t)16 * ld, lregion + wave * 1024 + 512);
}

__device__ __forceinline__ short8 lds_frag(const ushort_t* region, int row, int q) {
  return *(const short8*)(region + row * 32 + (((q ^ (row >> 1)) & 3) << 3));
}

#define MFMA_16(AR, B0, B1, J0, J1)                                            \
  __builtin_amdgcn_s_setprio(1);                                               \
  _Pragma("unroll")                                                            \
  for (int i = 0; i < 8; ++i) {                                                \
    acc[i][J0] = __builtin_amdgcn_mfma_f32_16x16x32_bf16(AR[i], B0, acc[i][J0], 0, 0, 0); \
    acc[i][J1] = __builtin_amdgcn_mfma_f32_16x16x32_bf16(AR[i], B1, acc[i][J1], 0, 0, 0); \
  }                                                                            \
  __builtin_amdgcn_s_setprio(0);

#define INTERVAL_OPEN()                                                        \
  __builtin_amdgcn_s_barrier();                                                \
  asm volatile("s_waitcnt lgkmcnt(0)" ::: "memory");                           \
  __builtin_amdgcn_sched_barrier(0);

__device__ __forceinline__ void gemm8_core(
    const ushort_t* __restrict__ A, const ushort_t* __restrict__ B,
    int lda, int ldb, int K, ushort_t* smem, floatx4 (&acc)[8][4])
{
  const int tid = threadIdx.x;
  const int wave = tid >> 6, lane = tid & 63;
  const int wm = wave >> 2, wn = wave & 3;      // 2 (M) x 4 (N) wave grid
  const int lr = lane & 15, q = lane >> 4;
  const int NT = K >> 6;
  const int ra = wm * 128 + lr;   // wave's A-row base
  const int rb = wn * 64 + lr;    // wave's B-row base

  // Prologue: FIFO prefix (7 stages = 14 loads), drain kt0's first 4 regions.
  stage_half(A, lda, 0,  smem +     0, wave, lane);   // As0(0)
  stage_half(B, ldb, 0,  smem + 16384, wave, lane);   // Bs0(0)
  stage_half(A, lda, 32, smem +  8192, wave, lane);   // As1(0)
  stage_half(B, ldb, 32, smem + 24576, wave, lane);   // Bs1(0)
  stage_half(A, lda, 64, smem + 32768, wave, lane);   // As0(1)
  stage_half(B, ldb, 64, smem + 49152, wave, lane);   // Bs0(1)
  stage_half(A, lda, 96, smem + 40960, wave, lane);   // As1(1)
  asm volatile("s_waitcnt vmcnt(6)" ::: "memory");    // keep As0/Bs0/As1(1)
  __builtin_amdgcn_s_barrier();
  __builtin_amdgcn_sched_barrier(0);

  short8 ar[8], ar2[8], b0, b1, t0, t1, u0, u1;
  // prefetch for kt=0 I_0 (plays the role of I_3(kt-1))
#pragma unroll
  for (int i = 0; i < 8; ++i) ar[i] = lds_frag(smem, ra + i * 16, q);
  b0 = lds_frag(smem + 16384, rb,      q);
  b1 = lds_frag(smem + 16384, rb + 16, q);

  for (int kt = 0; kt < NT; ++kt) {
    ushort_t* const cur = smem + (kt & 1) * 32768;
    ushort_t* const nxt = smem + ((kt & 1) ^ 1) * 32768;
    const bool s1 = (kt + 1) < NT, s2 = (kt + 2) < NT;

    // ---- I_0: MFMA(s0 x nf01) ; pf {Bs0 r32/48, As1 frag 0..3} ; stage Bs1(kt+1)
    INTERVAL_OPEN()
    MFMA_16(ar, b0, b1, 0, 1)
    t0 = lds_frag(cur + 16384, rb + 32, q);
    t1 = lds_frag(cur + 16384, rb + 48, q);
#pragma unroll
    for (int i = 0; i < 4; ++i) ar2[i] = lds_frag(cur + 8192, ra + i * 16, q);
    if (s1) stage_half(B, ldb, (kt + 1) * 64 + 32, nxt + 24576, wave, lane);

    // ---- I_1: MFMA(s0 x nf23) ; pf {As1 frag 4..7, Bs1 r0/16} ; stage As0(kt+2)
    INTERVAL_OPEN()
    MFMA_16(ar, t0, t1, 2, 3)
#pragma unroll
    for (int i = 4; i < 8; ++i) ar2[i] = lds_frag(cur + 8192, ra + i * 16, q);
    u0 = lds_frag(cur + 24576, rb,      q);
    u1 = lds_frag(cur + 24576, rb + 16, q);
    if (s2) stage_half(A, lda, (kt + 2) * 64, cur, wave, lane);

    // ---- I_2: MFMA(s1 x nf01) ; pf {Bs1 r32/48} ; stage Bs0(kt+2) ; vmcnt(4)
    INTERVAL_OPEN()
    MFMA_16(ar2, u0, u1, 0, 1)
    t0 = lds_frag(cur + 24576, rb + 32, q);
    t1 = lds_frag(cur + 24576, rb + 48, q);
    if (s2) stage_half(B, ldb, (kt + 2) * 64, cur + 16384, wave, lane);
    if (s1) {
      if (s2) { asm volatile("s_waitcnt vmcnt(4)" ::: "memory"); }
      else    { asm volatile("s_waitcnt vmcnt(0)" ::: "memory"); }
    }

    // ---- I_3: MFMA(s1 x nf23) ; pf next-kt {As0, Bs0 r0/16} from nxt ; stage As1(kt+2)
    INTERVAL_OPEN()
    MFMA_16(ar2, t0, t1, 2, 3)
    if (s1) {
#pragma unroll
      for (int i = 0; i < 8; ++i) ar[i] = lds_frag(nxt, ra + i * 16, q);
      b0 = lds_frag(nxt + 16384, rb,      q);
      b1 = lds_frag(nxt + 16384, rb + 16, q);
    }
    if (s2) stage_half(A, lda, (kt + 2) * 64 + 32, cur + 8192, wave, lane);
  }
}

// ---------- quantize / pack ----------
__global__ __launch_bounds__(256) void k_quant_x(const float* __restrict__ X,
                                                 ushort_t* __restrict__ Xb) {
  size_t i = ((size_t)blockIdx.x * 256 + threadIdx.x) * 4;
  float4 v = *(const float4*)(X + i);
  *(ushort4*)(Xb + i) = make_ushort4(f2bf(v.x), f2bf(v.y), f2bf(v.z), f2bf(v.w));
}

__global__ __launch_bounds__(256) void k_quant_w(
    const float* __restrict__ Wq, const float* __restrict__ Wk,
    const float* __restrict__ Wv, ushort_t* __restrict__ W) {
  size_t i = ((size_t)blockIdx.x * 256 + threadIdx.x) * 4;
  int row = (int)(i >> 10), col = (int)(i & 1023);
  int sel = row >> 10, sr = row & 1023;
  const float* src = sel == 0 ? Wq : (sel == 1 ? Wk : Wv);
  float4 v = *(const float4*)(src + (size_t)sr * 1024 + col);
  *(ushort4*)(W + i) = make_ushort4(f2bf(v.x), f2bf(v.y), f2bf(v.z), f2bf(v.w));
}

__global__ __launch_bounds__(256) void k_bias_zero(
    const float* __restrict__ bq, const float* __restrict__ bk,
    const float* __restrict__ bv, float* __restrict__ bias,
    float* __restrict__ q2, float* __restrict__ k2, float* __restrict__ rsum) {
  int i = blockIdx.x * 256 + threadIdx.x;
  if (i < 1024)       bias[i] = bq[i];
  else if (i < 2048)  bias[i] = bk[i - 1024];
  else if (i < 3072)  bias[i] = bv[i - 2048];
  if (i < BATCH * S_LEN) { q2[i] = 0.f; k2[i] = 0.f; rsum[i] = 0.f; }
}

// ---------- GEMM 1: QKV projection (M=16384, N=3072, K=1024) ----------
__global__ __launch_bounds__(512, 2) void k_gemm_qkv(
    const ushort_t* __restrict__ Xb, const ushort_t* __restrict__ W,
    const float* __restrict__ bias,
    ushort_t* __restrict__ Q, ushort_t* __restrict__ Kp, ushort_t* __restrict__ V,
    float* __restrict__ q2, float* __restrict__ k2) {
  __shared__ __attribute__((aligned(16))) ushort_t smem[65536];
  const int mt = blockIdx.x * 256, nt = blockIdx.y * 256;
  floatx4 acc[8][4];
  const floatx4 z = {0.f, 0.f, 0.f, 0.f};
#pragma unroll
  for (int i = 0; i < 8; ++i)
#pragma unroll
    for (int j = 0; j < 4; ++j) acc[i][j] = z;

  gemm8_core(Xb + (size_t)mt * EMB, W + (size_t)nt * EMB, EMB, EMB, EMB, smem, acc);

  const int lane = threadIdx.x & 63, wave = threadIdx.x >> 6;
  const int wm = wave >> 2, wn = wave & 3;
  const int lr = lane & 15, q = lane >> 4;
  const int which = nt >> 10;        // 0=q 1=k 2=v  (256 | 1024 so no straddle)
  const int nc0 = nt & 1023;
  ushort_t* dst = which == 0 ? Q : (which == 1 ? Kp : V);
  float* sq = which == 0 ? q2 : k2;
  float bv4[4];
#pragma unroll
  for (int j = 0; j < 4; ++j) bv4[j] = bias[nt + wn * 64 + j * 16 + lr];

#pragma unroll
  for (int i = 0; i < 8; ++i) {
#pragma unroll
    for (int r = 0; r < 4; ++r) {
      const int g = mt + wm * 128 + i * 16 + q * 4 + r;
      const int t = g >> 3, b = g & 7;
      float ss = 0.f;
#pragma unroll
      for (int j = 0; j < 4; ++j) {
        const float val = acc[i][j][r] + bv4[j];
        dst[(size_t)(b * S_LEN + t) * EMB + nc0 + wn * 64 + j * 16 + lr] = f2bf(val);
        ss += val * val;
      }
      if (which < 2) {
        ss += __shfl_xor(ss, 1);
        ss += __shfl_xor(ss, 2);
        ss += __shfl_xor(ss, 4);
        ss += __shfl_xor(ss, 8);
        if (lr == 0) atomicAdd(&sq[b * S_LEN + t], ss);
      }
    }
  }
}

// ---------- transpose V[b][j][e] -> Vt[b][e][j] ----------
__global__ __launch_bounds__(256) void k_transpose(const ushort_t* __restrict__ V,
                                                   ushort_t* __restrict__ Vt) {
  __shared__ ushort_t tile[64][72];
  const int b = blockIdx.z, j0 = blockIdx.x * 64, e0 = blockIdx.y * 64;
  const ushort_t* src = V + ((size_t)b * S_LEN + j0) * EMB + e0;
  const int tid = threadIdx.x;
#pragma unroll
  for (int rep = 0; rep < 2; ++rep) {
    const int lin = rep * 256 + tid;
    const int j = lin >> 3, e8 = (lin & 7) * 8;
    *(uint4*)&tile[j][e8] = *(const uint4*)(src + (size_t)j * EMB + e8);
  }
  __syncthreads();
  ushort_t* dst = Vt + ((size_t)b * EMB + e0) * S_LEN + j0;
#pragma unroll
  for (int rep = 0; rep < 2; ++rep) {
    const int lin = rep * 256 + tid;
    const int e = lin >> 3, j8 = (lin & 7) * 8;
    ushort8 o;
#pragma unroll
    for (int m = 0; m < 8; ++m) o[m] = tile[j8 + m][e];
    *(ushort8*)(dst + (size_t)e * S_LEN + j8) = o;
  }
}

// ---------- GEMM 2: logits + exp (per batch: 2048 x 2048 x 1024) ----------
__global__ __launch_bounds__(512, 2) void k_logits(
    const ushort_t* __restrict__ Q, const ushort_t* __restrict__ Kp,
    const float* __restrict__ q2, const float* __restrict__ k2,
    ushort_t* __restrict__ P, float* __restrict__ rsum) {
  __shared__ __attribute__((aligned(16))) ushort_t smem[65536];
  const int b = blockIdx.z;
  const int mt = blockIdx.x * 256, nt = blockIdx.y * 256;
  floatx4 acc[8][4];
  const floatx4 z = {0.f, 0.f, 0.f, 0.f};
#pragma unroll
  for (int i = 0; i < 8; ++i)
#pragma unroll
    for (int j = 0; j < 4; ++j) acc[i][j] = z;

  gemm8_core(Q + ((size_t)b * S_LEN + mt) * EMB,
             Kp + ((size_t)b * S_LEN + nt) * EMB, EMB, EMB, EMB, smem, acc);

  const int lane = threadIdx.x & 63, wave = threadIdx.x >> 6;
  const int wm = wave >> 2, wn = wave & 3;
  const int lr = lane & 15, q = lane >> 4;
  float k2v[4];
#pragma unroll
  for (int j = 0; j < 4; ++j) k2v[j] = k2[b * S_LEN + nt + wn * 64 + j * 16 + lr];

#pragma unroll
  for (int i = 0; i < 8; ++i) {
#pragma unroll
    for (int r = 0; r < 4; ++r) {
      const int t = mt + wm * 128 + i * 16 + q * 4 + r;
      const float q2v = q2[b * S_LEN + t];
      float ss = 0.f;
#pragma unroll
      for (int j = 0; j < 4; ++j) {
        float d2 = q2v + k2v[j] - 2.f * acc[i][j][r];
        d2 = fmaxf(d2, 0.f);
        const float p = __expf(-GAMMA * d2);
        P[((size_t)b * S_LEN + t) * S_LEN + nt + wn * 64 + j * 16 + lr] = f2bf(p);
        ss += p;
      }
      ss += __shfl_xor(ss, 1);
      ss += __shfl_xor(ss, 2);
      ss += __shfl_xor(ss, 4);
      ss += __shfl_xor(ss, 8);
      if (lr == 0) atomicAdd(&rsum[b * S_LEN + t], ss);
    }
  }
}

// ---------- GEMM 3: O = (P @ V) / rowsum (per batch: 2048 x 1024 x 2048) ----------
__global__ __launch_bounds__(512, 2) void k_out(
    const ushort_t* __restrict__ P, const ushort_t* __restrict__ Vt,
    const float* __restrict__ rsum, float* __restrict__ out) {
  __shared__ __attribute__((aligned(16))) ushort_t smem[65536];
  const int b = blockIdx.z;
  const int mt = blockIdx.x * 256, nt = blockIdx.y * 256;
  floatx4 acc[8][4];
  const floatx4 z = {0.f, 0.f, 0.f, 0.f};
#pragma unroll
  for (int i = 0; i < 8; ++i)
#pragma unroll
    for (int j = 0; j < 4; ++j) acc[i][j] = z;

  gemm8_core(P + ((size_t)b * S_LEN + mt) * S_LEN,
             Vt + ((size_t)b * EMB + nt) * S_LEN, S_LEN, S_LEN, S_LEN, smem, acc);

  const int lane = threadIdx.x & 63, wave = threadIdx.x >> 6;
  const int wm = wave >> 2, wn = wave & 3;
  const int lr = lane & 15, q = lane >> 4;
#pragma unroll
  for (int i = 0; i < 8; ++i) {
#pragma unroll
    for (int r = 0; r < 4; ++r) {
      const int t = mt + wm * 128 + i * 16 + q * 4 + r;
      const float rinv = 1.f / rsum[b * S_LEN + t];
#pragma unroll
      for (int j = 0; j < 4; ++j) {
        const int e = nt + wn * 64 + j * 16 + lr;
        out[((size_t)t * BATCH + b) * EMB + e] = acc[i][j][r] * rinv;
      }
    }
  }
}

extern "C" void kernel_launch(void* const* d_in, const int* in_sizes, int n_in,
                              void* d_out, int out_size, void* d_ws, size_t ws_size,
                              hipStream_t stream) {
  (void)in_sizes; (void)n_in; (void)out_size; (void)ws_size;
  const float* X  = (const float*)d_in[0];
  const float* Wq = (const float*)d_in[1];
  const float* bq = (const float*)d_in[2];
  const float* Wk = (const float*)d_in[3];
  const float* bk = (const float*)d_in[4];
  const float* Wv = (const float*)d_in[5];
  const float* bv = (const float*)d_in[6];
  float* out = (float*)d_out;
  char* ws = (char*)d_ws;

  // workspace layout (bytes); Xb aliases P (Xb dead before P is written)
  ushort_t* Q    = (ushort_t*)(ws + 0);           //  33,554,432
  ushort_t* Kp   = (ushort_t*)(ws + 33554432);    //  33,554,432
  ushort_t* V    = (ushort_t*)(ws + 67108864);    //  33,554,432
  ushort_t* Vt   = (ushort_t*)(ws + 100663296);   //  33,554,432
  ushort_t* P    = (ushort_t*)(ws + 134217728);   //  67,108,864
  ushort_t* Xb   = (ushort_t*)(ws + 134217728);   //  alias of P[0:33.5M]
  ushort_t* Wqkv = (ushort_t*)(ws + 201326592);   //   6,291,456
  float*    bias = (float*)(ws + 207618048);      //      12,288
  float*    q2   = (float*)(ws + 207630336);      //      65,536
  float*    k2   = (float*)(ws + 207695872);      //      65,536
  float*    rsum = (float*)(ws + 207761408);      //      65,536  -> total ~198 MiB

  k_quant_x <<<16384, 256, 0, stream>>>(X, Xb);
  k_quant_w <<<3072, 256, 0, stream>>>(Wq, Wk, Wv, Wqkv);
  k_bias_zero<<<64, 256, 0, stream>>>(bq, bk, bv, bias, q2, k2, rsum);
  k_gemm_qkv<<<dim3(64, 12), 512, 0, stream>>>(Xb, Wqkv, bias, Q, Kp, V, q2, k2);
  k_transpose<<<dim3(32, 16, 8), 256, 0, stream>>>(V, Vt);
  k_logits  <<<dim3(8, 8, 8), 512, 0, stream>>>(Q, Kp, q2, k2, P, rsum);
  k_out     <<<dim3(8, 4, 8), 512, 0, stream>>>(P, Vt, rsum, out);
}